// Round 16
// baseline (865.047 us; speedup 1.0000x reference)
//
#include <hip/hip_runtime.h>
#include <hip/hip_fp16.h>
#include <stdint.h>

typedef __attribute__((ext_vector_type(8))) _Float16 f16x8;
typedef __attribute__((ext_vector_type(4))) float f32x4;
typedef __attribute__((ext_vector_type(8))) short s16x8;

#define MFMA_F16(a, b, c) __builtin_amdgcn_mfma_f32_16x16x32_f16((a), (b), (c), 0, 0, 0)
#define MFMA_BF16(a, b, c) __builtin_amdgcn_mfma_f32_16x16x32_bf16((a), (b), (c), 0, 0, 0)

// ---------- helpers ----------
__device__ __forceinline__ uint32_t pack_hi2(float f0, float f1, float& r0, float& r1) {
  uint32_t b0 = __float_as_uint(f0), b1 = __float_as_uint(f1);
  r0 = f0 - __uint_as_float(b0 & 0xFFFF0000u);
  r1 = f1 - __uint_as_float(b1 & 0xFFFF0000u);
  return (b1 & 0xFFFF0000u) | (b0 >> 16);
}
__device__ __forceinline__ uint32_t pack_lo2(float r0, float r1) {
  return (__float_as_uint(r1) & 0xFFFF0000u) | (__float_as_uint(r0) >> 16);
}
__device__ __forceinline__ uint32_t f16rn(float f) {
  return (uint32_t)__half_as_ushort(__float2half_rn(f));
}
__device__ __forceinline__ float f16tof(uint32_t h) {
  return __half2float(__ushort_as_half((unsigned short)h));
}

// JAX Threefry-2x32, key=(0,42); partitionable: bits = o1^o2, ctr=(0, flat_idx)
__device__ __forceinline__ uint2 threefry2x32_42(uint32_t x0, uint32_t x1) {
  const uint32_t ks0 = 0u, ks1 = 42u, ks2 = 0x1BD11BDAu ^ 42u;
  x0 += ks0; x1 += ks1;
#define TF_R(rot) { x0 += x1; x1 = ((x1 << rot) | (x1 >> (32 - rot))); x1 ^= x0; }
  TF_R(13) TF_R(15) TF_R(26) TF_R(6)   x0 += ks1; x1 += ks2 + 1u;
  TF_R(17) TF_R(29) TF_R(16) TF_R(24)  x0 += ks2; x1 += ks0 + 2u;
  TF_R(13) TF_R(15) TF_R(26) TF_R(6)   x0 += ks0; x1 += ks1 + 3u;
  TF_R(17) TF_R(29) TF_R(16) TF_R(24)  x0 += ks1; x1 += ks2 + 4u;
  TF_R(13) TF_R(15) TF_R(26) TF_R(6)   x0 += ks2; x1 += ks0 + 5u;
#undef TF_R
  return make_uint2(x0, x1);
}
__device__ __forceinline__ bool keep_bit(uint32_t j) {
  uint2 tf = threefry2x32_42(0u, j);
  uint32_t bits = tf.x ^ tf.y;
  return (__uint_as_float(0x3F800000u | (bits >> 9)) - 1.0f) < 0.9f;
}

// ============================================================================
// w_splitT: W[k][n] f32 -> WhT/WlT[n][k] bf16 trunc-split (gemm1 B operand)
// ============================================================================
__global__ __launch_bounds__(256) void w_splitT(const float* __restrict__ W,
    uint16_t* __restrict__ WhT, uint16_t* __restrict__ WlT) {
  __shared__ uint16_t th[64][72];
  __shared__ uint16_t tl[64][72];
  const int t = threadIdx.x;
  const int n0 = blockIdx.x * 64;
  const int k0 = blockIdx.y * 64;
  const int rr = t >> 2;
  const int cq = (t & 3) * 16;
  const float* src = W + (size_t)(k0 + rr) * 1024 + n0 + cq;
#pragma unroll
  for (int q = 0; q < 4; ++q) {
    float4 v = ((const float4*)src)[q];
    float e[4] = {v.x, v.y, v.z, v.w};
#pragma unroll
    for (int j = 0; j < 4; ++j) {
      uint32_t b = __float_as_uint(e[j]);
      float rem = e[j] - __uint_as_float(b & 0xFFFF0000u);
      th[cq + q * 4 + j][rr] = (uint16_t)(b >> 16);
      tl[cq + q * 4 + j][rr] = (uint16_t)(__float_as_uint(rem) >> 16);
    }
  }
  __syncthreads();
  size_t dst = (size_t)(n0 + rr) * 1024 + k0 + cq;
  *(uint4*)&WhT[dst] = *(const uint4*)&th[rr][cq];
  *(uint4*)&WhT[dst + 8] = *(const uint4*)&th[rr][cq + 8];
  *(uint4*)&WlT[dst] = *(const uint4*)&tl[rr][cq];
  *(uint4*)&WlT[dst + 8] = *(const uint4*)&tl[rr][cq + 8];
}

// ============================================================================
// Kernel 1 (ws path): Y = X @ W, split-3 bf16 MFMA; W pre-split.
// Register-prefetch pipeline. Epilogue writes fp16 Yh only.
// ============================================================================
__global__ __launch_bounds__(256, 3) void bilin_gemm1w(
    const float* __restrict__ X, const uint16_t* __restrict__ WhT,
    const uint16_t* __restrict__ WlT, uint16_t* __restrict__ Yh) {
  __shared__ uint16_t sAh[128][40];
  __shared__ uint16_t sAl[128][40];
  __shared__ uint16_t sBh[128][40];
  __shared__ uint16_t sBl[128][40];

  const int t = threadIdx.x;
  const int lane = t & 63;
  const int wv = t >> 6;
  const int wm = wv >> 1, wn = wv & 1;
  const int lc = lane & 15, lg = lane >> 4;
  const int M0 = blockIdx.y * 128;
  const int N0 = blockIdx.x * 128;

  const f32x4 fzero = {0.f, 0.f, 0.f, 0.f};
  f32x4 acc[4][4];
#pragma unroll
  for (int i = 0; i < 4; ++i)
#pragma unroll
    for (int j = 0; j < 4; ++j) acc[i][j] = fzero;

  const int ar = t >> 1;
  const int ak = (t & 1) * 16;
  const int bc = t & 127;
  const int bq = t >> 7;

  const float* aptr = X + (size_t)(M0 + ar) * 1024 + ak;
  const uint16_t* whp = WhT + (size_t)(N0 + bc) * 1024 + bq * 16;
  const uint16_t* wlp = WlT + (size_t)(N0 + bc) * 1024 + bq * 16;

  float4 rA0, rA1, rA2, rA3;
  uint4 rBh0, rBh1, rBl0, rBl1;

  auto loadT = [&](int k0) {
    const float4* s = (const float4*)(aptr + k0);
    rA0 = s[0]; rA1 = s[1]; rA2 = s[2]; rA3 = s[3];
    rBh0 = ((const uint4*)(whp + k0))[0];
    rBh1 = ((const uint4*)(whp + k0))[1];
    rBl0 = ((const uint4*)(wlp + k0))[0];
    rBl1 = ((const uint4*)(wlp + k0))[1];
  };
  auto writeT = [&]() {
    float r0, r1, r2, r3, r4, r5, r6, r7, r8, r9, rA, rB, rC, rD, rE, rF;
    uint32_t h0 = pack_hi2(rA0.x, rA0.y, r0, r1);
    uint32_t h1 = pack_hi2(rA0.z, rA0.w, r2, r3);
    uint32_t h2 = pack_hi2(rA1.x, rA1.y, r4, r5);
    uint32_t h3 = pack_hi2(rA1.z, rA1.w, r6, r7);
    uint32_t h4 = pack_hi2(rA2.x, rA2.y, r8, r9);
    uint32_t h5 = pack_hi2(rA2.z, rA2.w, rA, rB);
    uint32_t h6 = pack_hi2(rA3.x, rA3.y, rC, rD);
    uint32_t h7 = pack_hi2(rA3.z, rA3.w, rE, rF);
    *(uint4*)&sAh[ar][ak + 0] = make_uint4(h0, h1, h2, h3);
    *(uint4*)&sAh[ar][ak + 8] = make_uint4(h4, h5, h6, h7);
    *(uint4*)&sAl[ar][ak + 0] =
        make_uint4(pack_lo2(r0, r1), pack_lo2(r2, r3), pack_lo2(r4, r5), pack_lo2(r6, r7));
    *(uint4*)&sAl[ar][ak + 8] =
        make_uint4(pack_lo2(r8, r9), pack_lo2(rA, rB), pack_lo2(rC, rD), pack_lo2(rE, rF));
    *(uint4*)&sBh[bc][bq * 16 + 0] = rBh0;
    *(uint4*)&sBh[bc][bq * 16 + 8] = rBh1;
    *(uint4*)&sBl[bc][bq * 16 + 0] = rBl0;
    *(uint4*)&sBl[bc][bq * 16 + 8] = rBl1;
  };

  loadT(0);
  writeT();
  __syncthreads();
  for (int it = 0; it < 32; ++it) {
    if (it < 31) loadT((it + 1) * 32);
    s16x8 ah[4], al[4];
#pragma unroll
    for (int mi = 0; mi < 4; ++mi) {
      ah[mi] = *(const s16x8*)&sAh[wm * 64 + mi * 16 + lc][lg * 8];
      al[mi] = *(const s16x8*)&sAl[wm * 64 + mi * 16 + lc][lg * 8];
    }
#pragma unroll
    for (int ni = 0; ni < 4; ++ni) {
      s16x8 bh = *(const s16x8*)&sBh[wn * 64 + ni * 16 + lc][lg * 8];
      s16x8 bl = *(const s16x8*)&sBl[wn * 64 + ni * 16 + lc][lg * 8];
#pragma unroll
      for (int mi = 0; mi < 4; ++mi) {
        acc[mi][ni] = MFMA_BF16(ah[mi], bh, acc[mi][ni]);
        acc[mi][ni] = MFMA_BF16(ah[mi], bl, acc[mi][ni]);
        acc[mi][ni] = MFMA_BF16(al[mi], bh, acc[mi][ni]);
      }
    }
    if (it < 31) {
      __syncthreads();
      writeT();
      __syncthreads();
    }
  }
#pragma unroll
  for (int mi = 0; mi < 4; ++mi)
#pragma unroll
    for (int ni = 0; ni < 4; ++ni)
#pragma unroll
      for (int r = 0; r < 4; ++r) {
        size_t idx = (size_t)(M0 + wm * 64 + mi * 16 + lg * 4 + r) * 1024 +
                     N0 + wn * 64 + ni * 16 + lc;
        Yh[idx] = (uint16_t)f16rn(acc[mi][ni][r]);
      }
}

// ============================================================================
// pre_prep: X -> XhT (fp16, transposed [b][d][key]); optionally Xh row-major
// ============================================================================
__global__ __launch_bounds__(256) void pre_prep(const float* __restrict__ X,
    uint16_t* __restrict__ XhT, uint16_t* __restrict__ Xh) {
  __shared__ uint16_t tile[64][72];
  const int t = threadIdx.x;
  const int b = blockIdx.z;
  const int d0 = blockIdx.x * 64;
  const int k0 = blockIdx.y * 64;
  const int rr = t >> 2;
  const int cq = (t & 3) * 16;
  const float* src = X + (size_t)(b * 2048 + k0 + rr) * 1024 + d0 + cq;
  uint16_t hv[16];
#pragma unroll
  for (int q = 0; q < 4; ++q) {
    float4 v = ((const float4*)src)[q];
    hv[q * 4 + 0] = (uint16_t)f16rn(v.x);
    hv[q * 4 + 1] = (uint16_t)f16rn(v.y);
    hv[q * 4 + 2] = (uint16_t)f16rn(v.z);
    hv[q * 4 + 3] = (uint16_t)f16rn(v.w);
    tile[cq + q * 4 + 0][rr] = hv[q * 4 + 0];
    tile[cq + q * 4 + 1][rr] = hv[q * 4 + 1];
    tile[cq + q * 4 + 2][rr] = hv[q * 4 + 2];
    tile[cq + q * 4 + 3][rr] = hv[q * 4 + 3];
  }
  if (Xh) {
    size_t rowdst = (size_t)(b * 2048 + k0 + rr) * 1024 + d0 + cq;
    *(uint4*)&Xh[rowdst] = *(const uint4*)&hv[0];
    *(uint4*)&Xh[rowdst + 8] = *(const uint4*)&hv[8];
  }
  __syncthreads();
  uint16_t* dst = XhT + (size_t)(b * 1024 + d0 + rr) * 2048 + k0 + cq;
  *(uint4*)dst = *(const uint4*)&tile[rr][cq];
  *(uint4*)(dst + 8) = *(const uint4*)&tile[rr][cq + 8];
}

// ============================================================================
// Kernel B: S'' = masked(S - tile-row-max) fp16, Mt, Psum. 1-PASS
// (A = Yh fp16 only, B = X fp16 hi). Register-prefetch pipeline.
// ============================================================================
template <bool XH>
__global__ __launch_bounds__(256, 6) void bilin_score(
    const float* __restrict__ X, const uint16_t* __restrict__ Xh,
    const uint16_t* __restrict__ Yh,
    uint16_t* __restrict__ Sp, float* __restrict__ Mt, float* __restrict__ Psum) {
  __shared__ uint16_t sAh[128][40];
  __shared__ uint16_t sBh[128][40];
  __shared__ float pm[2][128];
  __shared__ float psr[2][128];
  __shared__ float cm[128];

  const int t = threadIdx.x;
  const int lane = t & 63;
  const int wv = t >> 6;
  const int wm = wv >> 1, wn = wv & 1;
  const int lc = lane & 15, lg = lane >> 4;

  const int bid = blockIdx.x;
  const int b = bid & 7;                // batch -> XCD affinity
  const int tl = bid >> 3;
  const int M0 = (tl & 15) * 128;       // q block
  const int ktile = tl >> 4;
  const int N0 = ktile * 128;           // key block

  const float* Xb = X + (size_t)b * 2048 * 1024;

  const f32x4 fzero = {0.f, 0.f, 0.f, 0.f};
  f32x4 acc[4][4];
#pragma unroll
  for (int i = 0; i < 4; ++i)
#pragma unroll
    for (int j = 0; j < 4; ++j) acc[i][j] = fzero;

  const int ar = t >> 1;                // row 0..127
  const int ak = (t & 1) * 16;          // col offset (elems)

  const uint16_t* yhp = Yh + (size_t)(b * 2048 + M0 + ar) * 1024 + ak;
  const uint16_t* xhp = XH ? Xh + (size_t)(b * 2048 + N0 + ar) * 1024 + ak
                           : (const uint16_t*)nullptr;

  uint4 rAh0, rAh1;
  uint4 rB0, rB1;
  float4 rBf0, rBf1, rBf2, rBf3;

  auto loadT = [&](int k0) {
    rAh0 = ((const uint4*)(yhp + k0))[0];
    rAh1 = ((const uint4*)(yhp + k0))[1];
    if constexpr (XH) {
      rB0 = ((const uint4*)(xhp + k0))[0];
      rB1 = ((const uint4*)(xhp + k0))[1];
    } else {
      const float4* bs = (const float4*)&Xb[(size_t)(N0 + ar) * 1024 + k0 + ak];
      rBf0 = bs[0]; rBf1 = bs[1]; rBf2 = bs[2]; rBf3 = bs[3];
    }
  };
  auto writeT = [&]() {
    *(uint4*)&sAh[ar][ak + 0] = rAh0;
    *(uint4*)&sAh[ar][ak + 8] = rAh1;
    if constexpr (XH) {
      *(uint4*)&sBh[ar][ak + 0] = rB0;
      *(uint4*)&sBh[ar][ak + 8] = rB1;
    } else {
      uint32_t h0 = f16rn(rBf0.x) | (f16rn(rBf0.y) << 16);
      uint32_t h1 = f16rn(rBf0.z) | (f16rn(rBf0.w) << 16);
      uint32_t h2 = f16rn(rBf1.x) | (f16rn(rBf1.y) << 16);
      uint32_t h3 = f16rn(rBf1.z) | (f16rn(rBf1.w) << 16);
      uint32_t h4 = f16rn(rBf2.x) | (f16rn(rBf2.y) << 16);
      uint32_t h5 = f16rn(rBf2.z) | (f16rn(rBf2.w) << 16);
      uint32_t h6 = f16rn(rBf3.x) | (f16rn(rBf3.y) << 16);
      uint32_t h7 = f16rn(rBf3.z) | (f16rn(rBf3.w) << 16);
      *(uint4*)&sBh[ar][ak + 0] = make_uint4(h0, h1, h2, h3);
      *(uint4*)&sBh[ar][ak + 8] = make_uint4(h4, h5, h6, h7);
    }
  };

  loadT(0);
  writeT();
  __syncthreads();
  for (int it = 0; it < 32; ++it) {
    if (it < 31) loadT((it + 1) * 32);
    f16x8 ah[4];
#pragma unroll
    for (int mi = 0; mi < 4; ++mi)
      ah[mi] = *(const f16x8*)&sAh[wm * 64 + mi * 16 + lc][lg * 8];
#pragma unroll
    for (int ni = 0; ni < 4; ++ni) {
      f16x8 bh = *(const f16x8*)&sBh[wn * 64 + ni * 16 + lc][lg * 8];
#pragma unroll
      for (int mi = 0; mi < 4; ++mi)
        acc[mi][ni] = MFMA_F16(ah[mi], bh, acc[mi][ni]);
    }
    if (it < 31) {
      __syncthreads();
      writeT();
      __syncthreads();
    }
  }

  // ---- per-tile row max ----
#pragma unroll
  for (int mi = 0; mi < 4; ++mi)
#pragma unroll
    for (int r = 0; r < 4; ++r) {
      float m = fmaxf(fmaxf(acc[mi][0][r], acc[mi][1][r]),
                      fmaxf(acc[mi][2][r], acc[mi][3][r]));
      m = fmaxf(m, __shfl_xor(m, 1, 64));
      m = fmaxf(m, __shfl_xor(m, 2, 64));
      m = fmaxf(m, __shfl_xor(m, 4, 64));
      m = fmaxf(m, __shfl_xor(m, 8, 64));
      if (lc == 0) pm[wn][wm * 64 + mi * 16 + lg * 4 + r] = m;
    }
  __syncthreads();
  if (t < 128) {
    float m = fmaxf(pm[0][t], pm[1][t]);
    cm[t] = m;
    Mt[((size_t)b * 16 + ktile) * 2048 + M0 + t] = m;
  }
  __syncthreads();

  // ---- row sums (unmasked) + masked S'' write (dropped -> fp16 -inf) ----
  uint16_t* Sb = Sp + (size_t)b * 2048 * 2048;
#pragma unroll
  for (int mi = 0; mi < 4; ++mi)
#pragma unroll
    for (int r = 0; r < 4; ++r) {
      const int rl = wm * 64 + mi * 16 + lg * 4 + r;
      const float m = cm[rl];
      const uint32_t jrow = (uint32_t)b * 4194304u + (uint32_t)(M0 + rl) * 2048u +
                            (uint32_t)(N0 + wn * 64) + (uint32_t)lc;
      float s = 0.0f;
#pragma unroll
      for (int ni = 0; ni < 4; ++ni) {
        float sv = acc[mi][ni][r] - m;
        s += __expf(sv);
        bool kp = keep_bit(jrow + ni * 16u);
        Sb[(size_t)(M0 + rl) * 2048 + N0 + wn * 64 + ni * 16 + lc] =
            kp ? (uint16_t)f16rn(sv) : (uint16_t)0xFC00u;
      }
      s += __shfl_xor(s, 1, 64);
      s += __shfl_xor(s, 2, 64);
      s += __shfl_xor(s, 4, 64);
      s += __shfl_xor(s, 8, 64);
      if (lc == 0) psr[wn][rl] = s;
    }
  __syncthreads();
  if (t < 128)
    Psum[((size_t)b * 16 + ktile) * 2048 + M0 + t] = psr[0][t] + psr[1][t];
}

// ============================================================================
// Kernel C: out = P @ V from masked S''. (unchanged)
// ============================================================================
__global__ __launch_bounds__(1024, 4) void bilin_pv(
    float* __restrict__ YO, const uint16_t* __restrict__ Sp,
    const float* __restrict__ Mt, const float* __restrict__ Psum,
    const uint16_t* __restrict__ XhT) {
  __shared__ __align__(16) uint16_t Pl[2][64][136];
  __shared__ float mts[64][17];
  __shared__ float mrowL[64], invL[64];

  const int t = threadIdx.x;
  const int lane = t & 63;
  const int wv = t >> 6;
  const int lc = lane & 15, lg = lane >> 4;

  const int b = blockIdx.x & 7;
  const int q0 = (blockIdx.x >> 3) * 64;

  const uint16_t* Sb = Sp + (size_t)b * 2048 * 2048;
  const uint16_t* Vb = XhT + (size_t)b * 1024 * 2048;

  const int row = t >> 4;
  const int sub = t & 15;

  {
    float mtv = Mt[((size_t)b * 16 + sub) * 2048 + q0 + row];
    float ps = Psum[((size_t)b * 16 + sub) * 2048 + q0 + row];
    mts[row][sub] = mtv;
    float m = mtv;
    m = fmaxf(m, __shfl_xor(m, 1, 64));
    m = fmaxf(m, __shfl_xor(m, 2, 64));
    m = fmaxf(m, __shfl_xor(m, 4, 64));
    m = fmaxf(m, __shfl_xor(m, 8, 64));
    float sc = ps * __expf(mtv - m);
    sc += __shfl_xor(sc, 1, 64);
    sc += __shfl_xor(sc, 2, 64);
    sc += __shfl_xor(sc, 4, 64);
    sc += __shfl_xor(sc, 8, 64);
    if (sub == 0) { mrowL[row] = m; invL[row] = 1.0f / (sc * 0.9f); }
  }
  __syncthreads();

  const f32x4 fzero = {0.f, 0.f, 0.f, 0.f};
  f32x4 acc[4][4];
#pragma unroll
  for (int i = 0; i < 4; ++i)
#pragma unroll
    for (int j = 0; j < 4; ++j) acc[i][j] = fzero;

  const int d0 = wv * 64;
  const float mrL = mrowL[row];

  auto stage = [&](uint4 su, int kt, int buf) {
    const float mdel = mts[row][kt] - mrL;
    float p0 = __expf(f16tof(su.x & 0xFFFFu) + mdel);
    float p1 = __expf(f16tof(su.x >> 16) + mdel);
    float p2 = __expf(f16tof(su.y & 0xFFFFu) + mdel);
    float p3 = __expf(f16tof(su.y >> 16) + mdel);
    float p4 = __expf(f16tof(su.z & 0xFFFFu) + mdel);
    float p5 = __expf(f16tof(su.z >> 16) + mdel);
    float p6 = __expf(f16tof(su.w & 0xFFFFu) + mdel);
    float p7 = __expf(f16tof(su.w >> 16) + mdel);
    uint32_t w0 = f16rn(p0) | (f16rn(p1) << 16);
    uint32_t w1 = f16rn(p2) | (f16rn(p3) << 16);
    uint32_t w2 = f16rn(p4) | (f16rn(p5) << 16);
    uint32_t w3 = f16rn(p6) | (f16rn(p7) << 16);
    *(uint4*)&Pl[buf][row][sub * 8] = make_uint4(w0, w1, w2, w3);
  };

  uint4 su = *(const uint4*)&Sb[(size_t)(q0 + row) * 2048 + 0 * 128 + sub * 8];
  stage(su, 0, 0);
  __syncthreads();

  for (int kt = 0; kt < 16; ++kt) {
    const int cb = kt & 1;
    uint4 sun;
    if (kt < 15)
      sun = *(const uint4*)&Sb[(size_t)(q0 + row) * 2048 + (kt + 1) * 128 + sub * 8];
#pragma unroll
    for (int kst = 0; kst < 4; ++kst) {
      f16x8 a0 = *(const f16x8*)&Pl[cb][0 * 16 + lc][kst * 32 + lg * 8];
      f16x8 a1 = *(const f16x8*)&Pl[cb][1 * 16 + lc][kst * 32 + lg * 8];
      f16x8 a2 = *(const f16x8*)&Pl[cb][2 * 16 + lc][kst * 32 + lg * 8];
      f16x8 a3 = *(const f16x8*)&Pl[cb][3 * 16 + lc][kst * 32 + lg * 8];
#pragma unroll
      for (int nc = 0; nc < 4; ++nc) {
        f16x8 v = *(const f16x8*)&Vb[(size_t)(d0 + nc * 16 + lc) * 2048 +
                                     kt * 128 + kst * 32 + lg * 8];
        acc[0][nc] = MFMA_F16(a0, v, acc[0][nc]);
        acc[1][nc] = MFMA_F16(a1, v, acc[1][nc]);
        acc[2][nc] = MFMA_F16(a2, v, acc[2][nc]);
        acc[3][nc] = MFMA_F16(a3, v, acc[3][nc]);
      }
    }
    if (kt < 15) stage(sun, kt + 1, cb ^ 1);
    __syncthreads();
  }

  float* outb = YO + (size_t)b * 2048 * 1024;
#pragma unroll
  for (int fr = 0; fr < 4; ++fr)
#pragma unroll
    for (int r = 0; r < 4; ++r) {
      const int rl = fr * 16 + lg * 4 + r;
      const float inv = invL[rl];
#pragma unroll
      for (int nc = 0; nc < 4; ++nc)
        outb[(size_t)(q0 + rl) * 1024 + d0 + nc * 16 + lc] = acc[fr][nc][r] * inv;
    }
}

// ============================================================================
// Fallback kernels (no workspace): unchanged.
// ============================================================================
__global__ __launch_bounds__(256, 3) void bilin_gemm1(
    const float* __restrict__ X, const float* __restrict__ W,
    uint32_t* __restrict__ Ypk) {
  __shared__ uint16_t sAh[128][40];
  __shared__ uint16_t sAl[128][40];
  __shared__ uint16_t sBh[128][40];
  __shared__ uint16_t sBl[128][40];

  const int t = threadIdx.x;
  const int lane = t & 63;
  const int wv = t >> 6;
  const int wm = wv >> 1, wn = wv & 1;
  const int lc = lane & 15, lg = lane >> 4;
  const int M0 = blockIdx.y * 128;
  const int N0 = blockIdx.x * 128;

  const f32x4 fzero = {0.f, 0.f, 0.f, 0.f};
  f32x4 acc[4][4];
#pragma unroll
  for (int i = 0; i < 4; ++i)
#pragma unroll
    for (int j = 0; j < 4; ++j) acc[i][j] = fzero;

  const int ar = t >> 1;
  const int ak = (t & 1) * 16;
  const int bc = t & 127;
  const int bq = t >> 7;

  const float* aptr = X + (size_t)(M0 + ar) * 1024 + ak;
  const float* bptr = W + (size_t)bq * 16 * 1024 + N0 + bc;

  for (int k0 = 0; k0 < 1024; k0 += 32) {
    {
      const float4* s = (const float4*)(aptr + k0);
#pragma unroll
      for (int q = 0; q < 2; ++q) {
        float4 v0 = s[q * 2 + 0];
        float4 v1 = s[q * 2 + 1];
        float r0, r1, r2, r3, r4, r5, r6, r7;
        uint32_t h0 = pack_hi2(v0.x, v0.y, r0, r1);
        uint32_t h1 = pack_hi2(v0.z, v0.w, r2, r3);
        uint32_t h2 = pack_hi2(v1.x, v1.y, r4, r5);
        uint32_t h3 = pack_hi2(v1.z, v1.w, r6, r7);
        uint32_t l0 = pack_lo2(r0, r1), l1 = pack_lo2(r2, r3);
        uint32_t l2 = pack_lo2(r4, r5), l3 = pack_lo2(r6, r7);
        *(uint4*)&sAh[ar][ak + q * 8] = make_uint4(h0, h1, h2, h3);
        *(uint4*)&sAl[ar][ak + q * 8] = make_uint4(l0, l1, l2, l3);
      }
    }
    {
      float v[16];
#pragma unroll
      for (int i = 0; i < 16; ++i) v[i] = bptr[(size_t)(k0 + i) * 1024];
      float r[16];
      uint32_t h[8], lo[8];
#pragma unroll
      for (int i = 0; i < 8; ++i) h[i] = pack_hi2(v[2 * i], v[2 * i + 1], r[2 * i], r[2 * i + 1]);
#pragma unroll
      for (int i = 0; i < 8; ++i) lo[i] = pack_lo2(r[2 * i], r[2 * i + 1]);
      *(uint4*)&sBh[bc][bq * 16 + 0] = make_uint4(h[0], h[1], h[2], h[3]);
      *(uint4*)&sBh[bc][bq * 16 + 8] = make_uint4(h[4], h[5], h[6], h[7]);
      *(uint4*)&sBl[bc][bq * 16 + 0] = make_uint4(lo[0], lo[1], lo[2], lo[3]);
      *(uint4*)&sBl[bc][bq * 16 + 8] = make_uint4(lo[4], lo[5], lo[6], lo[7]);
    }
    __syncthreads();
    s16x8 ah[4], al[4];
#pragma unroll
    for (int mi = 0; mi < 4; ++mi) {
      ah[mi] = *(const s16x8*)&sAh[wm * 64 + mi * 16 + lc][lg * 8];
      al[mi] = *(const s16x8*)&sAl[wm * 64 + mi * 16 + lc][lg * 8];
    }
#pragma unroll
    for (int ni = 0; ni < 4; ++ni) {
      s16x8 bh = *(const s16x8*)&sBh[wn * 64 + ni * 16 + lc][lg * 8];
      s16x8 bl = *(const s16x8*)&sBl[wn * 64 + ni * 16 + lc][lg * 8];
#pragma unroll
      for (int mi = 0; mi < 4; ++mi) {
        acc[mi][ni] = MFMA_BF16(ah[mi], bh, acc[mi][ni]);
        acc[mi][ni] = MFMA_BF16(ah[mi], bl, acc[mi][ni]);
        acc[mi][ni] = MFMA_BF16(al[mi], bh, acc[mi][ni]);
      }
    }
    __syncthreads();
  }
#pragma unroll
  for (int mi = 0; mi < 4; ++mi)
#pragma unroll
    for (int ni = 0; ni < 4; ++ni)
#pragma unroll
      for (int r = 0; r < 4; ++r) {
        float y = acc[mi][ni][r];
        uint32_t hb = f16rn(y);
        uint32_t lb = f16rn(y - f16tof(hb));
        int row = M0 + wm * 64 + mi * 16 + lg * 4 + r;
        int col = N0 + wn * 64 + ni * 16 + lc;
        Ypk[(size_t)row * 1024 + col] = (hb << 16) | lb;
      }
}

__global__ __launch_bounds__(512, 4) void bilin_flash2f(
    const float* __restrict__ X, float* __restrict__ YO) {
  __shared__ __align__(16) uint16_t kbuf[2][2][128][40];
  __shared__ __align__(16) uint16_t qbuf[2][2][32][40];
  __shared__ __align__(16) uint16_t Pl[32][136];
  __shared__ float red[8][16];
  __shared__ float mrow[32], lrow[32], frow[32];
  uint16_t* vbase = &kbuf[0][0][0][0];

  const int t = threadIdx.x;
  const int lane = t & 63;
  const int wv = t >> 6;
  const int wr = wv >> 2, wc = wv & 3;
  const int lc = lane & 15, lg = lane >> 4;
  const int b = blockIdx.x & 7;
  const int q0 = (blockIdx.x >> 3) * 32;

  const float* Xb = X + (size_t)b * 2048 * 1024;
  const uint32_t* Ypk = (const uint32_t*)YO;

  if (t < 32) { mrow[t] = -1e30f; lrow[t] = 0.0f; }

  const f32x4 fzero = {0.f, 0.f, 0.f, 0.f};
  f32x4 acc_pv[16];
#pragma unroll
  for (int c = 0; c < 16; ++c) acc_pv[c] = fzero;

  const int myrow = wr * 16 + lg * 4;
  const int qsr = t >> 3;
  const int qsc = (t & 7) * 4;
  const int ksk = t >> 2;
  const int ksd = (t & 3) * 8;
  const int vkp = t & 63;
  const int vdg = t >> 6;

  for (int kb = 0; kb < 16; ++kb) {
    const int kbase = kb * 128;
    __syncthreads();

    f32x4 acc_s0 = fzero, acc_s1 = fzero;
    uint4 qld;
    float4 kf0, kf1;

    auto load_q = [&](int dd) {
      if (t < 256) qld = *(const uint4*)&Ypk[(size_t)(b * 2048 + q0 + qsr) * 1024 + dd + qsc];
    };
    auto write_q = [&](int nb) {
      if (t < 256) {
        uint32_t hh0 = (qld.x >> 16) | (qld.y & 0xFFFF0000u);
        uint32_t hh1 = (qld.z >> 16) | (qld.w & 0xFFFF0000u);
        uint32_t ll0 = (qld.x & 0xFFFFu) | (qld.y << 16);
        uint32_t ll1 = (qld.z & 0xFFFFu) | (qld.w << 16);
        *(uint2*)&qbuf[nb][0][qsr][qsc] = make_uint2(hh0, hh1);
        *(uint2*)&qbuf[nb][1][qsr][qsc] = make_uint2(ll0, ll1);
      }
    };
    auto load_k = [&](int dd) {
      const float* s = &Xb[(size_t)(kbase + ksk) * 1024 + dd + ksd];
      kf0 = ((const float4*)s)[0];
      kf1 = ((const float4*)s)[1];
    };
    auto write_k = [&](int nb) {
      float e[8] = {kf0.x, kf0.y, kf0.z, kf0.w, kf1.x, kf1.y, kf1.z, kf1.w};
      uint32_t h[8], l[8];
#pragma unroll
      for (int j = 0; j < 8; ++j) {
        h[j] = f16rn(e[j]);
        l[j] = f16rn(e[j] - f16tof(h[j]));
      }
      *(uint4*)&kbuf[nb][0][ksk][ksd] =
          make_uint4(h[0] | (h[1] << 16), h[2] | (h[3] << 16), h[4] | (h[5] << 16), h[6] | (h[7] << 16));
      *(uint4*)&kbuf[nb][1][ksk][ksd] =
          make_uint4(l[0] | (l[1] << 16), l[2] | (l[3] << 16), l[4] | (l[5] << 16), l[6] | (l[7] << 16));
    };

    load_q(0); load_k(0);
    write_q(0); write_k(0);
    __syncthreads();
#pragma unroll 2
    for (int dc = 0; dc < 32; ++dc) {
      const int cb = dc & 1;
      if (dc < 31) { load_q((dc + 1) * 32); load_k((dc + 1) * 32); }
      f16x8 ah = *(const f16x8*)&qbuf[cb][0][wr * 16 + lc][lg * 8];
      f16x8 al = *(const f16x8*)&qbuf[cb][1][wr * 16 + lc][lg * 8];
      {
        f16x8 bh = *(const f16x8*)&kbuf[cb][0][wc * 32 + lc][lg * 8];
        f16x8 bl = *(const f16x8*)&kbuf[cb][1][wc * 32 + lc][lg * 8];
        acc_s0 = MFMA_F16(ah, bh, acc_s0);
        acc_s0 = MFMA_F16(ah, bl, acc_s0);
        acc_s0 = MFMA_F16(al, bh, acc_s0);
      }
      {
        f16x8 bh = *(const f16x8*)&kbuf[cb][0][wc * 32 + 16 + lc][lg * 8];
        f16x8 bl = *(const f16x8*)&kbuf[cb][1][wc * 32 + 16 + lc][lg * 8];
        acc_s1 = MFMA_F16(ah, bh, acc_s1);
        acc_s1 = MFMA_F16(ah, bl, acc_s1);
        acc_s1 = MFMA_F16(al, bh, acc_s1);
      }
      if (dc < 31) { write_q(cb ^ 1); write_k(cb ^ 1); __syncthreads(); }
    }

#pragma unroll
    for (int r = 0; r < 4; ++r) {
      float m = fmaxf(acc_s0[r], acc_s1[r]);
      m = fmaxf(m, __shfl_xor(m, 1, 64));
      m = fmaxf(m, __shfl_xor(m, 2, 64));
      m = fmaxf(m, __shfl_xor(m, 4, 64));
      m = fmaxf(m, __shfl_xor(m, 8, 64));
      if (lc == 0) red[wv][lg * 4 + r] = m;
    }
    __syncthreads();
    if (t < 32) {
      int wrr = t >> 4, rr = t & 15;
      float mk = fmaxf(fmaxf(red[wrr * 4 + 0][rr], red[wrr * 4 + 1][rr]),
                       fmaxf(red[wrr * 4 + 2][rr], red[wrr * 4 + 3][rr]));
      float mo = mrow[t], mn = fmaxf(mo, mk);
      mrow[t] = mn;
      frow[t] = __expf(mo - mn);
    }
    __syncthreads();
#pragma unroll
    for (int r = 0; r < 4; ++r) {
      const int row = myrow + r;
      const float mn = mrow[row];
      float p0 = __expf(acc_s0[r] - mn);
      float p1 = __expf(acc_s1[r] - mn);
      float s = p0 + p1;
      s += __shfl_xor(s, 1, 64);
      s += __shfl_xor(s, 2, 64);
      s += __shfl_xor(s, 4, 64);
      s += __shfl_xor(s, 8, 64);
      if (lc == 0) red[wv][lg * 4 + r] = s;
      uint32_t jr = (uint32_t)b * 4194304u + (uint32_t)(q0 + row) * 2048u +
                    (uint32_t)(kbase + wc * 32 + lc);
      bool k0 = keep_bit(jr);
      bool k1 = keep_bit(jr + 16u);
      Pl[row][wc * 32 + lc] = k0 ? (uint16_t)f16rn(p0) : (uint16_t)0;
      Pl[row][wc * 32 + 16 + lc] = k1 ? (uint16_t)f16rn(p1) : (uint16_t)0;
    }
    __syncthreads();
    if (t < 32) {
      int wrr = t >> 4, rr = t & 15;
      lrow[t] = lrow[t] * frow[t] + (red[wrr * 4 + 0][rr] + red[wrr * 4 + 1][rr] +
                                     red[wrr * 4 + 2][rr] + red[wrr * 4 + 3][rr]);
    }

    {
      float fr[4];
#pragma unroll
      for (int r = 0; r < 4; ++r) fr[r] = frow[myrow + r];
#pragma unroll
      for (int c = 0; c < 16; ++c)
#pragma unroll
        for (int r = 0; r < 4; ++r) acc_pv[c][r] *= fr[r];
    }
    f16x8 ap0 = *(const f16x8*)&Pl[wr * 16 + lc][0 * 32 + lg * 8];
    f16x8 ap1 = *(const f16x8*)&Pl[wr * 16 + lc][1 * 32 + lg * 8];
    f16x8 ap2 = *(const f16x8*)&Pl[wr * 16 + lc][2 * 32 + lg * 8];
    f16x8 ap3 = *(const f16x8*)&Pl[wr * 16 + lc][3 * 32 + lg * 8];

    float4 vf0, vf1, vf2, vf3;
    auto load_v = [&](int c) {
      const float* s0 = &Xb[(size_t)(kbase + vkp * 2) * 1024 + c * 64 + vdg * 8];
      vf0 = ((const float4*)s0)[0];
      vf1 = ((const float4*)s0)[1];
      vf2 = ((const float4*)(s0 + 1024))[0];
      vf3 = ((const float4*)(s0 + 1024))[1];
    };
    auto write_v = [&](int nb) {
      uint16_t* vt = vbase + nb * (64 * 136);
      float a[8] = {vf0.x, vf0.y, vf0.z, vf0.w, vf1.x, vf1.y, vf1.z, vf1.w};
      float b2[8] = {vf2.x, vf2.y, vf2.z, vf2.w, vf3.x, vf3.y, vf3.z, vf3.w};
#pragma unroll
      for (int j = 0; j < 8; ++j)
        *(uint32_t*)&vt[(vdg * 8 + j) * 136 + vkp * 2] = f16rn(a[j]) | (f16rn(b2[j]) << 16);
    };

    load_v(0); write_v(0);
    __syncthreads();
#pragma unroll
    for (int c = 0; c < 16; ++c) {
      const int cb = c & 1;
      if (c < 15) load_v(c + 1);
      const uint16_t* vt = vbase + cb * (64 * 136);
      f16x8 bf0 = *(const f16x8*)&vt[(wc * 16 + lc) * 136 + 0 * 32 + lg * 8];
      f16x8 bf1 = *(const f16x8*)&vt[(wc * 16 + lc) * 136 + 1 * 32 + lg * 8];
      f16x8 bf2 = *(const f16x8*)&vt[(wc * 16 + lc) * 136 + 2 * 32 + lg * 8];
      f16x8 bf3 = *(const f16x8*)&vt[(wc * 16 + lc) * 136 + 3 * 32 + lg * 8];
      acc_pv[c] = MFMA_F16(ap0, bf0, acc_pv[c]);
      acc_pv[c] = MFMA_F16(ap1, bf1, acc_pv[c]);
      acc_pv[c] = MFMA_F16(ap2, bf2, acc_pv[c]);
      acc_pv[c] = MFMA_F16(ap3, bf3, acc_pv[c]);
      if (c < 15) { write_v(cb ^ 1); __syncthreads(); }
    }
  }  // kb

  __syncthreads();
  float inv[4];
#pragma unroll
  for (int r = 0; r < 4; ++r) inv[r] = 1.0f / (lrow[myrow + r] * 0.9f);
  float* outb = YO + (size_t)b * 2048 * 1024;
#pragma unroll
  for (int c = 0; c < 16; ++c)
#pragma unroll
    for (int r = 0; r < 4; ++r)
      outb[(size_t)(q0 + myrow + r) * 1024 + c * 64 + wc * 16 + lc] = acc_pv[c][r] * inv[r];
}

// ============================================================================
extern "C" void kernel_launch(void* const* d_in, const int* in_sizes, int n_in,
                              void* d_out, int out_size, void* d_ws, size_t ws_size,
                              hipStream_t stream) {
  (void)in_sizes; (void)n_in; (void)out_size;
  const float* X = (const float*)d_in[0];
  const float* W = (const float*)d_in[1];
  const bool mid = ws_size >= 104857600ULL;                // 100 MiB (proven)
  const bool big = ws_size >= 140509184ULL;                // +Xh region

  if (mid) {
    uint16_t* XhT = (uint16_t*)d_ws;
    uint16_t* Sp = (uint16_t*)((char*)d_ws + 33554432);
    uint16_t* WhT = (uint16_t*)((char*)d_ws + 100663296);
    uint16_t* WlT = (uint16_t*)((char*)d_ws + 100663296 + 2097152);
    float* Mt = (float*)((char*)d_ws + 100663296);
    float* Psum = (float*)((char*)d_ws + 100663296 + 1048576);
    uint16_t* Xh = big ? (uint16_t*)((char*)d_ws + 106954752) : nullptr;
    uint16_t* Yh = (uint16_t*)d_out;

    w_splitT<<<dim3(16, 16), 256, 0, stream>>>(W, WhT, WlT);
    bilin_gemm1w<<<dim3(8, 128), 256, 0, stream>>>(X, WhT, WlT, Yh);
    pre_prep<<<dim3(16, 32, 8), 256, 0, stream>>>(X, XhT, Xh);
    if (big)
      bilin_score<true><<<2048, 256, 0, stream>>>(X, Xh, Yh, Sp, Mt, Psum);
    else
      bilin_score<false><<<2048, 256, 0, stream>>>(X, nullptr, Yh, Sp, Mt, Psum);
    bilin_pv<<<256, 1024, 0, stream>>>((float*)d_out, Sp, Mt, Psum, XhT);
  } else {
    bilin_gemm1<<<dim3(8, 128), 256, 0, stream>>>(X, W, (uint32_t*)d_out);
    bilin_flash2f<<<512, 512, 0, stream>>>(X, (float*)d_out);
  }
}

// Round 17
// 478.655 us; speedup vs baseline: 1.8072x; 1.8072x over previous
//
#include <hip/hip_runtime.h>
#include <hip/hip_fp16.h>
#include <stdint.h>

typedef __attribute__((ext_vector_type(8))) _Float16 f16x8;
typedef __attribute__((ext_vector_type(4))) float f32x4;
typedef __attribute__((ext_vector_type(8))) short s16x8;

#define MFMA_F16(a, b, c) __builtin_amdgcn_mfma_f32_16x16x32_f16((a), (b), (c), 0, 0, 0)
#define MFMA_BF16(a, b, c) __builtin_amdgcn_mfma_f32_16x16x32_bf16((a), (b), (c), 0, 0, 0)

// ---------- helpers ----------
__device__ __forceinline__ uint32_t pack_hi2(float f0, float f1, float& r0, float& r1) {
  uint32_t b0 = __float_as_uint(f0), b1 = __float_as_uint(f1);
  r0 = f0 - __uint_as_float(b0 & 0xFFFF0000u);
  r1 = f1 - __uint_as_float(b1 & 0xFFFF0000u);
  return (b1 & 0xFFFF0000u) | (b0 >> 16);
}
__device__ __forceinline__ uint32_t pack_lo2(float r0, float r1) {
  return (__float_as_uint(r1) & 0xFFFF0000u) | (__float_as_uint(r0) >> 16);
}
__device__ __forceinline__ uint32_t f16rn(float f) {
  return (uint32_t)__half_as_ushort(__float2half_rn(f));
}
__device__ __forceinline__ float f16tof(uint32_t h) {
  return __half2float(__ushort_as_half((unsigned short)h));
}

// JAX Threefry-2x32, key=(0,42); partitionable: bits = o1^o2, ctr=(0, flat_idx)
__device__ __forceinline__ uint2 threefry2x32_42(uint32_t x0, uint32_t x1) {
  const uint32_t ks0 = 0u, ks1 = 42u, ks2 = 0x1BD11BDAu ^ 42u;
  x0 += ks0; x1 += ks1;
#define TF_R(rot) { x0 += x1; x1 = ((x1 << rot) | (x1 >> (32 - rot))); x1 ^= x0; }
  TF_R(13) TF_R(15) TF_R(26) TF_R(6)   x0 += ks1; x1 += ks2 + 1u;
  TF_R(17) TF_R(29) TF_R(16) TF_R(24)  x0 += ks2; x1 += ks0 + 2u;
  TF_R(13) TF_R(15) TF_R(26) TF_R(6)   x0 += ks0; x1 += ks1 + 3u;
  TF_R(17) TF_R(29) TF_R(16) TF_R(24)  x0 += ks1; x1 += ks2 + 4u;
  TF_R(13) TF_R(15) TF_R(26) TF_R(6)   x0 += ks2; x1 += ks0 + 5u;
#undef TF_R
  return make_uint2(x0, x1);
}
__device__ __forceinline__ bool keep_bit(uint32_t j) {
  uint2 tf = threefry2x32_42(0u, j);
  uint32_t bits = tf.x ^ tf.y;
  return (__uint_as_float(0x3F800000u | (bits >> 9)) - 1.0f) < 0.9f;
}

// ============================================================================
// w_splitT: W[k][n] f32 -> WhT/WlT[n][k] bf16 trunc-split (gemm1 B operand)
// ============================================================================
__global__ __launch_bounds__(256) void w_splitT(const float* __restrict__ W,
    uint16_t* __restrict__ WhT, uint16_t* __restrict__ WlT) {
  __shared__ uint16_t th[64][72];
  __shared__ uint16_t tl[64][72];
  const int t = threadIdx.x;
  const int n0 = blockIdx.x * 64;
  const int k0 = blockIdx.y * 64;
  const int rr = t >> 2;
  const int cq = (t & 3) * 16;
  const float* src = W + (size_t)(k0 + rr) * 1024 + n0 + cq;
#pragma unroll
  for (int q = 0; q < 4; ++q) {
    float4 v = ((const float4*)src)[q];
    float e[4] = {v.x, v.y, v.z, v.w};
#pragma unroll
    for (int j = 0; j < 4; ++j) {
      uint32_t b = __float_as_uint(e[j]);
      float rem = e[j] - __uint_as_float(b & 0xFFFF0000u);
      th[cq + q * 4 + j][rr] = (uint16_t)(b >> 16);
      tl[cq + q * 4 + j][rr] = (uint16_t)(__float_as_uint(rem) >> 16);
    }
  }
  __syncthreads();
  size_t dst = (size_t)(n0 + rr) * 1024 + k0 + cq;
  *(uint4*)&WhT[dst] = *(const uint4*)&th[rr][cq];
  *(uint4*)&WhT[dst + 8] = *(const uint4*)&th[rr][cq + 8];
  *(uint4*)&WlT[dst] = *(const uint4*)&tl[rr][cq];
  *(uint4*)&WlT[dst + 8] = *(const uint4*)&tl[rr][cq + 8];
}

// ============================================================================
// Kernel 1 (ws path): Y = X @ W, split-3 bf16 MFMA; W pre-split.
// Register-prefetch pipeline. Epilogue writes fp16 Yh only.
// ============================================================================
__global__ __launch_bounds__(256, 3) void bilin_gemm1w(
    const float* __restrict__ X, const uint16_t* __restrict__ WhT,
    const uint16_t* __restrict__ WlT, uint16_t* __restrict__ Yh) {
  __shared__ uint16_t sAh[128][40];
  __shared__ uint16_t sAl[128][40];
  __shared__ uint16_t sBh[128][40];
  __shared__ uint16_t sBl[128][40];

  const int t = threadIdx.x;
  const int lane = t & 63;
  const int wv = t >> 6;
  const int wm = wv >> 1, wn = wv & 1;
  const int lc = lane & 15, lg = lane >> 4;
  const int M0 = blockIdx.y * 128;
  const int N0 = blockIdx.x * 128;

  const f32x4 fzero = {0.f, 0.f, 0.f, 0.f};
  f32x4 acc[4][4];
#pragma unroll
  for (int i = 0; i < 4; ++i)
#pragma unroll
    for (int j = 0; j < 4; ++j) acc[i][j] = fzero;

  const int ar = t >> 1;
  const int ak = (t & 1) * 16;
  const int bc = t & 127;
  const int bq = t >> 7;

  const float* aptr = X + (size_t)(M0 + ar) * 1024 + ak;
  const uint16_t* whp = WhT + (size_t)(N0 + bc) * 1024 + bq * 16;
  const uint16_t* wlp = WlT + (size_t)(N0 + bc) * 1024 + bq * 16;

  float4 rA0, rA1, rA2, rA3;
  uint4 rBh0, rBh1, rBl0, rBl1;

  auto loadT = [&](int k0) {
    const float4* s = (const float4*)(aptr + k0);
    rA0 = s[0]; rA1 = s[1]; rA2 = s[2]; rA3 = s[3];
    rBh0 = ((const uint4*)(whp + k0))[0];
    rBh1 = ((const uint4*)(whp + k0))[1];
    rBl0 = ((const uint4*)(wlp + k0))[0];
    rBl1 = ((const uint4*)(wlp + k0))[1];
  };
  auto writeT = [&]() {
    float r0, r1, r2, r3, r4, r5, r6, r7, r8, r9, rA, rB, rC, rD, rE, rF;
    uint32_t h0 = pack_hi2(rA0.x, rA0.y, r0, r1);
    uint32_t h1 = pack_hi2(rA0.z, rA0.w, r2, r3);
    uint32_t h2 = pack_hi2(rA1.x, rA1.y, r4, r5);
    uint32_t h3 = pack_hi2(rA1.z, rA1.w, r6, r7);
    uint32_t h4 = pack_hi2(rA2.x, rA2.y, r8, r9);
    uint32_t h5 = pack_hi2(rA2.z, rA2.w, rA, rB);
    uint32_t h6 = pack_hi2(rA3.x, rA3.y, rC, rD);
    uint32_t h7 = pack_hi2(rA3.z, rA3.w, rE, rF);
    *(uint4*)&sAh[ar][ak + 0] = make_uint4(h0, h1, h2, h3);
    *(uint4*)&sAh[ar][ak + 8] = make_uint4(h4, h5, h6, h7);
    *(uint4*)&sAl[ar][ak + 0] =
        make_uint4(pack_lo2(r0, r1), pack_lo2(r2, r3), pack_lo2(r4, r5), pack_lo2(r6, r7));
    *(uint4*)&sAl[ar][ak + 8] =
        make_uint4(pack_lo2(r8, r9), pack_lo2(rA, rB), pack_lo2(rC, rD), pack_lo2(rE, rF));
    *(uint4*)&sBh[bc][bq * 16 + 0] = rBh0;
    *(uint4*)&sBh[bc][bq * 16 + 8] = rBh1;
    *(uint4*)&sBl[bc][bq * 16 + 0] = rBl0;
    *(uint4*)&sBl[bc][bq * 16 + 8] = rBl1;
  };

  loadT(0);
  writeT();
  __syncthreads();
  for (int it = 0; it < 32; ++it) {
    if (it < 31) loadT((it + 1) * 32);
    s16x8 ah[4], al[4];
#pragma unroll
    for (int mi = 0; mi < 4; ++mi) {
      ah[mi] = *(const s16x8*)&sAh[wm * 64 + mi * 16 + lc][lg * 8];
      al[mi] = *(const s16x8*)&sAl[wm * 64 + mi * 16 + lc][lg * 8];
    }
#pragma unroll
    for (int ni = 0; ni < 4; ++ni) {
      s16x8 bh = *(const s16x8*)&sBh[wn * 64 + ni * 16 + lc][lg * 8];
      s16x8 bl = *(const s16x8*)&sBl[wn * 64 + ni * 16 + lc][lg * 8];
#pragma unroll
      for (int mi = 0; mi < 4; ++mi) {
        acc[mi][ni] = MFMA_BF16(ah[mi], bh, acc[mi][ni]);
        acc[mi][ni] = MFMA_BF16(ah[mi], bl, acc[mi][ni]);
        acc[mi][ni] = MFMA_BF16(al[mi], bh, acc[mi][ni]);
      }
    }
    if (it < 31) {
      __syncthreads();
      writeT();
      __syncthreads();
    }
  }
#pragma unroll
  for (int mi = 0; mi < 4; ++mi)
#pragma unroll
    for (int ni = 0; ni < 4; ++ni)
#pragma unroll
      for (int r = 0; r < 4; ++r) {
        size_t idx = (size_t)(M0 + wm * 64 + mi * 16 + lg * 4 + r) * 1024 +
                     N0 + wn * 64 + ni * 16 + lc;
        Yh[idx] = (uint16_t)f16rn(acc[mi][ni][r]);
      }
}

// ============================================================================
// pre_prep: X -> XhT (fp16, transposed [b][d][key]); optionally Xh row-major
// ============================================================================
__global__ __launch_bounds__(256) void pre_prep(const float* __restrict__ X,
    uint16_t* __restrict__ XhT, uint16_t* __restrict__ Xh) {
  __shared__ uint16_t tile[64][72];
  const int t = threadIdx.x;
  const int b = blockIdx.z;
  const int d0 = blockIdx.x * 64;
  const int k0 = blockIdx.y * 64;
  const int rr = t >> 2;
  const int cq = (t & 3) * 16;
  const float* src = X + (size_t)(b * 2048 + k0 + rr) * 1024 + d0 + cq;
  uint16_t hv[16];
#pragma unroll
  for (int q = 0; q < 4; ++q) {
    float4 v = ((const float4*)src)[q];
    hv[q * 4 + 0] = (uint16_t)f16rn(v.x);
    hv[q * 4 + 1] = (uint16_t)f16rn(v.y);
    hv[q * 4 + 2] = (uint16_t)f16rn(v.z);
    hv[q * 4 + 3] = (uint16_t)f16rn(v.w);
    tile[cq + q * 4 + 0][rr] = hv[q * 4 + 0];
    tile[cq + q * 4 + 1][rr] = hv[q * 4 + 1];
    tile[cq + q * 4 + 2][rr] = hv[q * 4 + 2];
    tile[cq + q * 4 + 3][rr] = hv[q * 4 + 3];
  }
  if (Xh) {
    size_t rowdst = (size_t)(b * 2048 + k0 + rr) * 1024 + d0 + cq;
    *(uint4*)&Xh[rowdst] = *(const uint4*)&hv[0];
    *(uint4*)&Xh[rowdst + 8] = *(const uint4*)&hv[8];
  }
  __syncthreads();
  uint16_t* dst = XhT + (size_t)(b * 1024 + d0 + rr) * 2048 + k0 + cq;
  *(uint4*)dst = *(const uint4*)&tile[rr][cq];
  *(uint4*)(dst + 8) = *(const uint4*)&tile[rr][cq + 8];
}

// ============================================================================
// Kernel B: S'' = masked(S - tile-row-max) fp16, Mt, Psum. 1-PASS
// (A = Yh fp16 only, B = X fp16 hi). Register-prefetch pipeline.
// __launch_bounds__(256,4): acc[4][4]=64 VGPR + staging needs >85 cap; (256,6)
// in r16 forced a spill (VGPR=40, 1.3GB scratch writes, 643us). Keep 4.
// ============================================================================
template <bool XH>
__global__ __launch_bounds__(256, 4) void bilin_score(
    const float* __restrict__ X, const uint16_t* __restrict__ Xh,
    const uint16_t* __restrict__ Yh,
    uint16_t* __restrict__ Sp, float* __restrict__ Mt, float* __restrict__ Psum) {
  __shared__ uint16_t sAh[128][40];
  __shared__ uint16_t sBh[128][40];
  __shared__ float pm[2][128];
  __shared__ float psr[2][128];
  __shared__ float cm[128];

  const int t = threadIdx.x;
  const int lane = t & 63;
  const int wv = t >> 6;
  const int wm = wv >> 1, wn = wv & 1;
  const int lc = lane & 15, lg = lane >> 4;

  const int bid = blockIdx.x;
  const int b = bid & 7;                // batch -> XCD affinity
  const int tl = bid >> 3;
  const int M0 = (tl & 15) * 128;       // q block
  const int ktile = tl >> 4;
  const int N0 = ktile * 128;           // key block

  const float* Xb = X + (size_t)b * 2048 * 1024;

  const f32x4 fzero = {0.f, 0.f, 0.f, 0.f};
  f32x4 acc[4][4];
#pragma unroll
  for (int i = 0; i < 4; ++i)
#pragma unroll
    for (int j = 0; j < 4; ++j) acc[i][j] = fzero;

  const int ar = t >> 1;                // row 0..127
  const int ak = (t & 1) * 16;          // col offset (elems)

  const uint16_t* yhp = Yh + (size_t)(b * 2048 + M0 + ar) * 1024 + ak;
  const uint16_t* xhp = XH ? Xh + (size_t)(b * 2048 + N0 + ar) * 1024 + ak
                           : (const uint16_t*)nullptr;

  uint4 rAh0, rAh1;
  uint4 rB0, rB1;
  float4 rBf0, rBf1, rBf2, rBf3;

  auto loadT = [&](int k0) {
    rAh0 = ((const uint4*)(yhp + k0))[0];
    rAh1 = ((const uint4*)(yhp + k0))[1];
    if constexpr (XH) {
      rB0 = ((const uint4*)(xhp + k0))[0];
      rB1 = ((const uint4*)(xhp + k0))[1];
    } else {
      const float4* bs = (const float4*)&Xb[(size_t)(N0 + ar) * 1024 + k0 + ak];
      rBf0 = bs[0]; rBf1 = bs[1]; rBf2 = bs[2]; rBf3 = bs[3];
    }
  };
  auto writeT = [&]() {
    *(uint4*)&sAh[ar][ak + 0] = rAh0;
    *(uint4*)&sAh[ar][ak + 8] = rAh1;
    if constexpr (XH) {
      *(uint4*)&sBh[ar][ak + 0] = rB0;
      *(uint4*)&sBh[ar][ak + 8] = rB1;
    } else {
      uint32_t h0 = f16rn(rBf0.x) | (f16rn(rBf0.y) << 16);
      uint32_t h1 = f16rn(rBf0.z) | (f16rn(rBf0.w) << 16);
      uint32_t h2 = f16rn(rBf1.x) | (f16rn(rBf1.y) << 16);
      uint32_t h3 = f16rn(rBf1.z) | (f16rn(rBf1.w) << 16);
      uint32_t h4 = f16rn(rBf2.x) | (f16rn(rBf2.y) << 16);
      uint32_t h5 = f16rn(rBf2.z) | (f16rn(rBf2.w) << 16);
      uint32_t h6 = f16rn(rBf3.x) | (f16rn(rBf3.y) << 16);
      uint32_t h7 = f16rn(rBf3.z) | (f16rn(rBf3.w) << 16);
      *(uint4*)&sBh[ar][ak + 0] = make_uint4(h0, h1, h2, h3);
      *(uint4*)&sBh[ar][ak + 8] = make_uint4(h4, h5, h6, h7);
    }
  };

  loadT(0);
  writeT();
  __syncthreads();
  for (int it = 0; it < 32; ++it) {
    if (it < 31) loadT((it + 1) * 32);
    f16x8 ah[4];
#pragma unroll
    for (int mi = 0; mi < 4; ++mi)
      ah[mi] = *(const f16x8*)&sAh[wm * 64 + mi * 16 + lc][lg * 8];
#pragma unroll
    for (int ni = 0; ni < 4; ++ni) {
      f16x8 bh = *(const f16x8*)&sBh[wn * 64 + ni * 16 + lc][lg * 8];
#pragma unroll
      for (int mi = 0; mi < 4; ++mi)
        acc[mi][ni] = MFMA_F16(ah[mi], bh, acc[mi][ni]);
    }
    if (it < 31) {
      __syncthreads();
      writeT();
      __syncthreads();
    }
  }

  // ---- per-tile row max ----
#pragma unroll
  for (int mi = 0; mi < 4; ++mi)
#pragma unroll
    for (int r = 0; r < 4; ++r) {
      float m = fmaxf(fmaxf(acc[mi][0][r], acc[mi][1][r]),
                      fmaxf(acc[mi][2][r], acc[mi][3][r]));
      m = fmaxf(m, __shfl_xor(m, 1, 64));
      m = fmaxf(m, __shfl_xor(m, 2, 64));
      m = fmaxf(m, __shfl_xor(m, 4, 64));
      m = fmaxf(m, __shfl_xor(m, 8, 64));
      if (lc == 0) pm[wn][wm * 64 + mi * 16 + lg * 4 + r] = m;
    }
  __syncthreads();
  if (t < 128) {
    float m = fmaxf(pm[0][t], pm[1][t]);
    cm[t] = m;
    Mt[((size_t)b * 16 + ktile) * 2048 + M0 + t] = m;
  }
  __syncthreads();

  // ---- row sums (unmasked) + masked S'' write (dropped -> fp16 -inf) ----
  uint16_t* Sb = Sp + (size_t)b * 2048 * 2048;
#pragma unroll
  for (int mi = 0; mi < 4; ++mi)
#pragma unroll
    for (int r = 0; r < 4; ++r) {
      const int rl = wm * 64 + mi * 16 + lg * 4 + r;
      const float m = cm[rl];
      const uint32_t jrow = (uint32_t)b * 4194304u + (uint32_t)(M0 + rl) * 2048u +
                            (uint32_t)(N0 + wn * 64) + (uint32_t)lc;
      float s = 0.0f;
#pragma unroll
      for (int ni = 0; ni < 4; ++ni) {
        float sv = acc[mi][ni][r] - m;
        s += __expf(sv);
        bool kp = keep_bit(jrow + ni * 16u);
        Sb[(size_t)(M0 + rl) * 2048 + N0 + wn * 64 + ni * 16 + lc] =
            kp ? (uint16_t)f16rn(sv) : (uint16_t)0xFC00u;
      }
      s += __shfl_xor(s, 1, 64);
      s += __shfl_xor(s, 2, 64);
      s += __shfl_xor(s, 4, 64);
      s += __shfl_xor(s, 8, 64);
      if (lc == 0) psr[wn][rl] = s;
    }
  __syncthreads();
  if (t < 128)
    Psum[((size_t)b * 16 + ktile) * 2048 + M0 + t] = psr[0][t] + psr[1][t];
}

// ============================================================================
// Kernel C: out = P @ V from masked S''. (unchanged)
// ============================================================================
__global__ __launch_bounds__(1024, 4) void bilin_pv(
    float* __restrict__ YO, const uint16_t* __restrict__ Sp,
    const float* __restrict__ Mt, const float* __restrict__ Psum,
    const uint16_t* __restrict__ XhT) {
  __shared__ __align__(16) uint16_t Pl[2][64][136];
  __shared__ float mts[64][17];
  __shared__ float mrowL[64], invL[64];

  const int t = threadIdx.x;
  const int lane = t & 63;
  const int wv = t >> 6;
  const int lc = lane & 15, lg = lane >> 4;

  const int b = blockIdx.x & 7;
  const int q0 = (blockIdx.x >> 3) * 64;

  const uint16_t* Sb = Sp + (size_t)b * 2048 * 2048;
  const uint16_t* Vb = XhT + (size_t)b * 1024 * 2048;

  const int row = t >> 4;
  const int sub = t & 15;

  {
    float mtv = Mt[((size_t)b * 16 + sub) * 2048 + q0 + row];
    float ps = Psum[((size_t)b * 16 + sub) * 2048 + q0 + row];
    mts[row][sub] = mtv;
    float m = mtv;
    m = fmaxf(m, __shfl_xor(m, 1, 64));
    m = fmaxf(m, __shfl_xor(m, 2, 64));
    m = fmaxf(m, __shfl_xor(m, 4, 64));
    m = fmaxf(m, __shfl_xor(m, 8, 64));
    float sc = ps * __expf(mtv - m);
    sc += __shfl_xor(sc, 1, 64);
    sc += __shfl_xor(sc, 2, 64);
    sc += __shfl_xor(sc, 4, 64);
    sc += __shfl_xor(sc, 8, 64);
    if (sub == 0) { mrowL[row] = m; invL[row] = 1.0f / (sc * 0.9f); }
  }
  __syncthreads();

  const f32x4 fzero = {0.f, 0.f, 0.f, 0.f};
  f32x4 acc[4][4];
#pragma unroll
  for (int i = 0; i < 4; ++i)
#pragma unroll
    for (int j = 0; j < 4; ++j) acc[i][j] = fzero;

  const int d0 = wv * 64;
  const float mrL = mrowL[row];

  auto stage = [&](uint4 su, int kt, int buf) {
    const float mdel = mts[row][kt] - mrL;
    float p0 = __expf(f16tof(su.x & 0xFFFFu) + mdel);
    float p1 = __expf(f16tof(su.x >> 16) + mdel);
    float p2 = __expf(f16tof(su.y & 0xFFFFu) + mdel);
    float p3 = __expf(f16tof(su.y >> 16) + mdel);
    float p4 = __expf(f16tof(su.z & 0xFFFFu) + mdel);
    float p5 = __expf(f16tof(su.z >> 16) + mdel);
    float p6 = __expf(f16tof(su.w & 0xFFFFu) + mdel);
    float p7 = __expf(f16tof(su.w >> 16) + mdel);
    uint32_t w0 = f16rn(p0) | (f16rn(p1) << 16);
    uint32_t w1 = f16rn(p2) | (f16rn(p3) << 16);
    uint32_t w2 = f16rn(p4) | (f16rn(p5) << 16);
    uint32_t w3 = f16rn(p6) | (f16rn(p7) << 16);
    *(uint4*)&Pl[buf][row][sub * 8] = make_uint4(w0, w1, w2, w3);
  };

  uint4 su = *(const uint4*)&Sb[(size_t)(q0 + row) * 2048 + 0 * 128 + sub * 8];
  stage(su, 0, 0);
  __syncthreads();

  for (int kt = 0; kt < 16; ++kt) {
    const int cb = kt & 1;
    uint4 sun;
    if (kt < 15)
      sun = *(const uint4*)&Sb[(size_t)(q0 + row) * 2048 + (kt + 1) * 128 + sub * 8];
#pragma unroll
    for (int kst = 0; kst < 4; ++kst) {
      f16x8 a0 = *(const f16x8*)&Pl[cb][0 * 16 + lc][kst * 32 + lg * 8];
      f16x8 a1 = *(const f16x8*)&Pl[cb][1 * 16 + lc][kst * 32 + lg * 8];
      f16x8 a2 = *(const f16x8*)&Pl[cb][2 * 16 + lc][kst * 32 + lg * 8];
      f16x8 a3 = *(const f16x8*)&Pl[cb][3 * 16 + lc][kst * 32 + lg * 8];
#pragma unroll
      for (int nc = 0; nc < 4; ++nc) {
        f16x8 v = *(const f16x8*)&Vb[(size_t)(d0 + nc * 16 + lc) * 2048 +
                                     kt * 128 + kst * 32 + lg * 8];
        acc[0][nc] = MFMA_F16(a0, v, acc[0][nc]);
        acc[1][nc] = MFMA_F16(a1, v, acc[1][nc]);
        acc[2][nc] = MFMA_F16(a2, v, acc[2][nc]);
        acc[3][nc] = MFMA_F16(a3, v, acc[3][nc]);
      }
    }
    if (kt < 15) stage(sun, kt + 1, cb ^ 1);
    __syncthreads();
  }

  float* outb = YO + (size_t)b * 2048 * 1024;
#pragma unroll
  for (int fr = 0; fr < 4; ++fr)
#pragma unroll
    for (int r = 0; r < 4; ++r) {
      const int rl = fr * 16 + lg * 4 + r;
      const float inv = invL[rl];
#pragma unroll
      for (int nc = 0; nc < 4; ++nc)
        outb[(size_t)(q0 + rl) * 1024 + d0 + nc * 16 + lc] = acc[fr][nc][r] * inv;
    }
}

// ============================================================================
// Fallback kernels (no workspace): unchanged.
// ============================================================================
__global__ __launch_bounds__(256, 3) void bilin_gemm1(
    const float* __restrict__ X, const float* __restrict__ W,
    uint32_t* __restrict__ Ypk) {
  __shared__ uint16_t sAh[128][40];
  __shared__ uint16_t sAl[128][40];
  __shared__ uint16_t sBh[128][40];
  __shared__ uint16_t sBl[128][40];

  const int t = threadIdx.x;
  const int lane = t & 63;
  const int wv = t >> 6;
  const int wm = wv >> 1, wn = wv & 1;
  const int lc = lane & 15, lg = lane >> 4;
  const int M0 = blockIdx.y * 128;
  const int N0 = blockIdx.x * 128;

  const f32x4 fzero = {0.f, 0.f, 0.f, 0.f};
  f32x4 acc[4][4];
#pragma unroll
  for (int i = 0; i < 4; ++i)
#pragma unroll
    for (int j = 0; j < 4; ++j) acc[i][j] = fzero;

  const int ar = t >> 1;
  const int ak = (t & 1) * 16;
  const int bc = t & 127;
  const int bq = t >> 7;

  const float* aptr = X + (size_t)(M0 + ar) * 1024 + ak;
  const float* bptr = W + (size_t)bq * 16 * 1024 + N0 + bc;

  for (int k0 = 0; k0 < 1024; k0 += 32) {
    {
      const float4* s = (const float4*)(aptr + k0);
#pragma unroll
      for (int q = 0; q < 2; ++q) {
        float4 v0 = s[q * 2 + 0];
        float4 v1 = s[q * 2 + 1];
        float r0, r1, r2, r3, r4, r5, r6, r7;
        uint32_t h0 = pack_hi2(v0.x, v0.y, r0, r1);
        uint32_t h1 = pack_hi2(v0.z, v0.w, r2, r3);
        uint32_t h2 = pack_hi2(v1.x, v1.y, r4, r5);
        uint32_t h3 = pack_hi2(v1.z, v1.w, r6, r7);
        uint32_t l0 = pack_lo2(r0, r1), l1 = pack_lo2(r2, r3);
        uint32_t l2 = pack_lo2(r4, r5), l3 = pack_lo2(r6, r7);
        *(uint4*)&sAh[ar][ak + q * 8] = make_uint4(h0, h1, h2, h3);
        *(uint4*)&sAl[ar][ak + q * 8] = make_uint4(l0, l1, l2, l3);
      }
    }
    {
      float v[16];
#pragma unroll
      for (int i = 0; i < 16; ++i) v[i] = bptr[(size_t)(k0 + i) * 1024];
      float r[16];
      uint32_t h[8], lo[8];
#pragma unroll
      for (int i = 0; i < 8; ++i) h[i] = pack_hi2(v[2 * i], v[2 * i + 1], r[2 * i], r[2 * i + 1]);
#pragma unroll
      for (int i = 0; i < 8; ++i) lo[i] = pack_lo2(r[2 * i], r[2 * i + 1]);
      *(uint4*)&sBh[bc][bq * 16 + 0] = make_uint4(h[0], h[1], h[2], h[3]);
      *(uint4*)&sBh[bc][bq * 16 + 8] = make_uint4(h[4], h[5], h[6], h[7]);
      *(uint4*)&sBl[bc][bq * 16 + 0] = make_uint4(lo[0], lo[1], lo[2], lo[3]);
      *(uint4*)&sBl[bc][bq * 16 + 8] = make_uint4(lo[4], lo[5], lo[6], lo[7]);
    }
    __syncthreads();
    s16x8 ah[4], al[4];
#pragma unroll
    for (int mi = 0; mi < 4; ++mi) {
      ah[mi] = *(const s16x8*)&sAh[wm * 64 + mi * 16 + lc][lg * 8];
      al[mi] = *(const s16x8*)&sAl[wm * 64 + mi * 16 + lc][lg * 8];
    }
#pragma unroll
    for (int ni = 0; ni < 4; ++ni) {
      s16x8 bh = *(const s16x8*)&sBh[wn * 64 + ni * 16 + lc][lg * 8];
      s16x8 bl = *(const s16x8*)&sBl[wn * 64 + ni * 16 + lc][lg * 8];
#pragma unroll
      for (int mi = 0; mi < 4; ++mi) {
        acc[mi][ni] = MFMA_BF16(ah[mi], bh, acc[mi][ni]);
        acc[mi][ni] = MFMA_BF16(ah[mi], bl, acc[mi][ni]);
        acc[mi][ni] = MFMA_BF16(al[mi], bh, acc[mi][ni]);
      }
    }
    __syncthreads();
  }
#pragma unroll
  for (int mi = 0; mi < 4; ++mi)
#pragma unroll
    for (int ni = 0; ni < 4; ++ni)
#pragma unroll
      for (int r = 0; r < 4; ++r) {
        float y = acc[mi][ni][r];
        uint32_t hb = f16rn(y);
        uint32_t lb = f16rn(y - f16tof(hb));
        int row = M0 + wm * 64 + mi * 16 + lg * 4 + r;
        int col = N0 + wn * 64 + ni * 16 + lc;
        Ypk[(size_t)row * 1024 + col] = (hb << 16) | lb;
      }
}

__global__ __launch_bounds__(512, 4) void bilin_flash2f(
    const float* __restrict__ X, float* __restrict__ YO) {
  __shared__ __align__(16) uint16_t kbuf[2][2][128][40];
  __shared__ __align__(16) uint16_t qbuf[2][2][32][40];
  __shared__ __align__(16) uint16_t Pl[32][136];
  __shared__ float red[8][16];
  __shared__ float mrow[32], lrow[32], frow[32];
  uint16_t* vbase = &kbuf[0][0][0][0];

  const int t = threadIdx.x;
  const int lane = t & 63;
  const int wv = t >> 6;
  const int wr = wv >> 2, wc = wv & 3;
  const int lc = lane & 15, lg = lane >> 4;
  const int b = blockIdx.x & 7;
  const int q0 = (blockIdx.x >> 3) * 32;

  const float* Xb = X + (size_t)b * 2048 * 1024;
  const uint32_t* Ypk = (const uint32_t*)YO;

  if (t < 32) { mrow[t] = -1e30f; lrow[t] = 0.0f; }

  const f32x4 fzero = {0.f, 0.f, 0.f, 0.f};
  f32x4 acc_pv[16];
#pragma unroll
  for (int c = 0; c < 16; ++c) acc_pv[c] = fzero;

  const int myrow = wr * 16 + lg * 4;
  const int qsr = t >> 3;
  const int qsc = (t & 7) * 4;
  const int ksk = t >> 2;
  const int ksd = (t & 3) * 8;
  const int vkp = t & 63;
  const int vdg = t >> 6;

  for (int kb = 0; kb < 16; ++kb) {
    const int kbase = kb * 128;
    __syncthreads();

    f32x4 acc_s0 = fzero, acc_s1 = fzero;
    uint4 qld;
    float4 kf0, kf1;

    auto load_q = [&](int dd) {
      if (t < 256) qld = *(const uint4*)&Ypk[(size_t)(b * 2048 + q0 + qsr) * 1024 + dd + qsc];
    };
    auto write_q = [&](int nb) {
      if (t < 256) {
        uint32_t hh0 = (qld.x >> 16) | (qld.y & 0xFFFF0000u);
        uint32_t hh1 = (qld.z >> 16) | (qld.w & 0xFFFF0000u);
        uint32_t ll0 = (qld.x & 0xFFFFu) | (qld.y << 16);
        uint32_t ll1 = (qld.z & 0xFFFFu) | (qld.w << 16);
        *(uint2*)&qbuf[nb][0][qsr][qsc] = make_uint2(hh0, hh1);
        *(uint2*)&qbuf[nb][1][qsr][qsc] = make_uint2(ll0, ll1);
      }
    };
    auto load_k = [&](int dd) {
      const float* s = &Xb[(size_t)(kbase + ksk) * 1024 + dd + ksd];
      kf0 = ((const float4*)s)[0];
      kf1 = ((const float4*)s)[1];
    };
    auto write_k = [&](int nb) {
      float e[8] = {kf0.x, kf0.y, kf0.z, kf0.w, kf1.x, kf1.y, kf1.z, kf1.w};
      uint32_t h[8], l[8];
#pragma unroll
      for (int j = 0; j < 8; ++j) {
        h[j] = f16rn(e[j]);
        l[j] = f16rn(e[j] - f16tof(h[j]));
      }
      *(uint4*)&kbuf[nb][0][ksk][ksd] =
          make_uint4(h[0] | (h[1] << 16), h[2] | (h[3] << 16), h[4] | (h[5] << 16), h[6] | (h[7] << 16));
      *(uint4*)&kbuf[nb][1][ksk][ksd] =
          make_uint4(l[0] | (l[1] << 16), l[2] | (l[3] << 16), l[4] | (l[5] << 16), l[6] | (l[7] << 16));
    };

    load_q(0); load_k(0);
    write_q(0); write_k(0);
    __syncthreads();
#pragma unroll 2
    for (int dc = 0; dc < 32; ++dc) {
      const int cb = dc & 1;
      if (dc < 31) { load_q((dc + 1) * 32); load_k((dc + 1) * 32); }
      f16x8 ah = *(const f16x8*)&qbuf[cb][0][wr * 16 + lc][lg * 8];
      f16x8 al = *(const f16x8*)&qbuf[cb][1][wr * 16 + lc][lg * 8];
      {
        f16x8 bh = *(const f16x8*)&kbuf[cb][0][wc * 32 + lc][lg * 8];
        f16x8 bl = *(const f16x8*)&kbuf[cb][1][wc * 32 + lc][lg * 8];
        acc_s0 = MFMA_F16(ah, bh, acc_s0);
        acc_s0 = MFMA_F16(ah, bl, acc_s0);
        acc_s0 = MFMA_F16(al, bh, acc_s0);
      }
      {
        f16x8 bh = *(const f16x8*)&kbuf[cb][0][wc * 32 + 16 + lc][lg * 8];
        f16x8 bl = *(const f16x8*)&kbuf[cb][1][wc * 32 + 16 + lc][lg * 8];
        acc_s1 = MFMA_F16(ah, bh, acc_s1);
        acc_s1 = MFMA_F16(ah, bl, acc_s1);
        acc_s1 = MFMA_F16(al, bh, acc_s1);
      }
      if (dc < 31) { write_q(cb ^ 1); write_k(cb ^ 1); __syncthreads(); }
    }

#pragma unroll
    for (int r = 0; r < 4; ++r) {
      float m = fmaxf(acc_s0[r], acc_s1[r]);
      m = fmaxf(m, __shfl_xor(m, 1, 64));
      m = fmaxf(m, __shfl_xor(m, 2, 64));
      m = fmaxf(m, __shfl_xor(m, 4, 64));
      m = fmaxf(m, __shfl_xor(m, 8, 64));
      if (lc == 0) red[wv][lg * 4 + r] = m;
    }
    __syncthreads();
    if (t < 32) {
      int wrr = t >> 4, rr = t & 15;
      float mk = fmaxf(fmaxf(red[wrr * 4 + 0][rr], red[wrr * 4 + 1][rr]),
                       fmaxf(red[wrr * 4 + 2][rr], red[wrr * 4 + 3][rr]));
      float mo = mrow[t], mn = fmaxf(mo, mk);
      mrow[t] = mn;
      frow[t] = __expf(mo - mn);
    }
    __syncthreads();
#pragma unroll
    for (int r = 0; r < 4; ++r) {
      const int row = myrow + r;
      const float mn = mrow[row];
      float p0 = __expf(acc_s0[r] - mn);
      float p1 = __expf(acc_s1[r] - mn);
      float s = p0 + p1;
      s += __shfl_xor(s, 1, 64);
      s += __shfl_xor(s, 2, 64);
      s += __shfl_xor(s, 4, 64);
      s += __shfl_xor(s, 8, 64);
      if (lc == 0) red[wv][lg * 4 + r] = s;
      uint32_t jr = (uint32_t)b * 4194304u + (uint32_t)(q0 + row) * 2048u +
                    (uint32_t)(kbase + wc * 32 + lc);
      bool k0 = keep_bit(jr);
      bool k1 = keep_bit(jr + 16u);
      Pl[row][wc * 32 + lc] = k0 ? (uint16_t)f16rn(p0) : (uint16_t)0;
      Pl[row][wc * 32 + 16 + lc] = k1 ? (uint16_t)f16rn(p1) : (uint16_t)0;
    }
    __syncthreads();
    if (t < 32) {
      int wrr = t >> 4, rr = t & 15;
      lrow[t] = lrow[t] * frow[t] + (red[wrr * 4 + 0][rr] + red[wrr * 4 + 1][rr] +
                                     red[wrr * 4 + 2][rr] + red[wrr * 4 + 3][rr]);
    }

    {
      float fr[4];
#pragma unroll
      for (int r = 0; r < 4; ++r) fr[r] = frow[myrow + r];
#pragma unroll
      for (int c = 0; c < 16; ++c)
#pragma unroll
        for (int r = 0; r < 4; ++r) acc_pv[c][r] *= fr[r];
    }
    f16x8 ap0 = *(const f16x8*)&Pl[wr * 16 + lc][0 * 32 + lg * 8];
    f16x8 ap1 = *(const f16x8*)&Pl[wr * 16 + lc][1 * 32 + lg * 8];
    f16x8 ap2 = *(const f16x8*)&Pl[wr * 16 + lc][2 * 32 + lg * 8];
    f16x8 ap3 = *(const f16x8*)&Pl[wr * 16 + lc][3 * 32 + lg * 8];

    float4 vf0, vf1, vf2, vf3;
    auto load_v = [&](int c) {
      const float* s0 = &Xb[(size_t)(kbase + vkp * 2) * 1024 + c * 64 + vdg * 8];
      vf0 = ((const float4*)s0)[0];
      vf1 = ((const float4*)s0)[1];
      vf2 = ((const float4*)(s0 + 1024))[0];
      vf3 = ((const float4*)(s0 + 1024))[1];
    };
    auto write_v = [&](int nb) {
      uint16_t* vt = vbase + nb * (64 * 136);
      float a[8] = {vf0.x, vf0.y, vf0.z, vf0.w, vf1.x, vf1.y, vf1.z, vf1.w};
      float b2[8] = {vf2.x, vf2.y, vf2.z, vf2.w, vf3.x, vf3.y, vf3.z, vf3.w};
#pragma unroll
      for (int j = 0; j < 8; ++j)
        *(uint32_t*)&vt[(vdg * 8 + j) * 136 + vkp * 2] = f16rn(a[j]) | (f16rn(b2[j]) << 16);
    };

    load_v(0); write_v(0);
    __syncthreads();
#pragma unroll
    for (int c = 0; c < 16; ++c) {
      const int cb = c & 1;
      if (c < 15) load_v(c + 1);
      const uint16_t* vt = vbase + cb * (64 * 136);
      f16x8 bf0 = *(const f16x8*)&vt[(wc * 16 + lc) * 136 + 0 * 32 + lg * 8];
      f16x8 bf1 = *(const f16x8*)&vt[(wc * 16 + lc) * 136 + 1 * 32 + lg * 8];
      f16x8 bf2 = *(const f16x8*)&vt[(wc * 16 + lc) * 136 + 2 * 32 + lg * 8];
      f16x8 bf3 = *(const f16x8*)&vt[(wc * 16 + lc) * 136 + 3 * 32 + lg * 8];
      acc_pv[c] = MFMA_F16(ap0, bf0, acc_pv[c]);
      acc_pv[c] = MFMA_F16(ap1, bf1, acc_pv[c]);
      acc_pv[c] = MFMA_F16(ap2, bf2, acc_pv[c]);
      acc_pv[c] = MFMA_F16(ap3, bf3, acc_pv[c]);
      if (c < 15) { write_v(cb ^ 1); __syncthreads(); }
    }
  }  // kb

  __syncthreads();
  float inv[4];
#pragma unroll
  for (int r = 0; r < 4; ++r) inv[r] = 1.0f / (lrow[myrow + r] * 0.9f);
  float* outb = YO + (size_t)b * 2048 * 1024;
#pragma unroll
  for (int c = 0; c < 16; ++c)
#pragma unroll
    for (int r = 0; r < 4; ++r)
      outb[(size_t)(q0 + myrow + r) * 1024 + c * 64 + wc * 16 + lc] = acc_pv[c][r] * inv[r];
}

// ============================================================================
extern "C" void kernel_launch(void* const* d_in, const int* in_sizes, int n_in,
                              void* d_out, int out_size, void* d_ws, size_t ws_size,
                              hipStream_t stream) {
  (void)in_sizes; (void)n_in; (void)out_size;
  const float* X = (const float*)d_in[0];
  const float* W = (const float*)d_in[1];
  const bool mid = ws_size >= 104857600ULL;                // 100 MiB (proven)
  const bool big = ws_size >= 140509184ULL;                // +Xh region

  if (mid) {
    uint16_t* XhT = (uint16_t*)d_ws;
    uint16_t* Sp = (uint16_t*)((char*)d_ws + 33554432);
    uint16_t* WhT = (uint16_t*)((char*)d_ws + 100663296);
    uint16_t* WlT = (uint16_t*)((char*)d_ws + 100663296 + 2097152);
    float* Mt = (float*)((char*)d_ws + 100663296);
    float* Psum = (float*)((char*)d_ws + 100663296 + 1048576);
    uint16_t* Xh = big ? (uint16_t*)((char*)d_ws + 106954752) : nullptr;
    uint16_t* Yh = (uint16_t*)d_out;

    w_splitT<<<dim3(16, 16), 256, 0, stream>>>(W, WhT, WlT);
    bilin_gemm1w<<<dim3(8, 128), 256, 0, stream>>>(X, WhT, WlT, Yh);
    pre_prep<<<dim3(16, 32, 8), 256, 0, stream>>>(X, XhT, Xh);
    if (big)
      bilin_score<true><<<2048, 256, 0, stream>>>(X, Xh, Yh, Sp, Mt, Psum);
    else
      bilin_score<false><<<2048, 256, 0, stream>>>(X, nullptr, Yh, Sp, Mt, Psum);
    bilin_pv<<<256, 1024, 0, stream>>>((float*)d_out, Sp, Mt, Psum, XhT);
  } else {
    bilin_gemm1<<<dim3(8, 128), 256, 0, stream>>>(X, W, (uint32_t*)d_out);
    bilin_flash2f<<<512, 512, 0, stream>>>(X, (float*)d_out);
  }
}